// Round 2
// baseline (333.644 us; speedup 1.0000x reference)
//
#include <hip/hip_runtime.h>

// RoPE2D cos/sin table generator — all float32.
// Output layout: [cos_2d (rows*dim)] ++ [sin_2d (rows*dim)], rows = H*W, dim = 128.
// Row p = y*W + x. Channel c:
//   c in [0, dimx):   freq = x * ifx[c % (dimx/2)]
//   c in [dimx, dim): freq = y * ify[(c-dimx) % (dimy/2)]
// Concat-duplication: each sincos value is stored at channel ci and ci + half.

typedef __attribute__((ext_vector_type(8))) float float8;

template <int TDX, int TDY>
__global__ __launch_bounds__(256) void rope2d_kernel(
    const float* __restrict__ ifx,
    const float* __restrict__ ify,
    const int* __restrict__ wptr,
    float* __restrict__ out,
    int rows, int rdx, int rdy)
{
    const int dimx = TDX ? TDX : rdx;          // 64 (compile-time in fast path)
    const int dimy = TDY ? TDY : rdy;          // 64
    const int dim  = dimx + dimy;              // 128
    const int tpr  = dim >> 4;                 // threads per row = 8
    const int halfx = dimx >> 1, halfy = dimy >> 1;   // 32, 32
    const int nx = halfx >> 3;                 // x-threads per row = 4
    const long long sin_off = (long long)rows * dim;

    int idx = blockIdx.x * blockDim.x + threadIdx.x;
    if (idx >= rows * tpr) return;

    int t = idx % tpr;          // folds to & 7 in templated instantiation
    int p = idx / tpr;          // folds to >> 3

    const int W = *wptr;        // uniform scalar load
    int xw, yh;
    if ((W & (W - 1)) == 0) {   // power-of-two width fast path
        const int s = __ffs(W) - 1;
        xw = p & (W - 1);
        yh = p >> s;
    } else {
        xw = p % W;
        yh = p / W;
    }

    float pos;
    const float* tab;
    int ci0, chbase, dup;
    if (t < nx) {               // x-dependent channels [0, dimx)
        pos = (float)xw;
        tab = ifx;
        ci0 = t << 3;           // 0,8,16,24
        chbase = ci0;
        dup = halfx;
    } else {                    // y-dependent channels [dimx, dim)
        pos = (float)yh;
        tab = ify;
        ci0 = (t - nx) << 3;
        chbase = dimx + ci0;
        dup = halfy;
    }

    // 8 contiguous f32 inv_freq entries (32B-aligned: ci0 multiple of 8)
    float8 fr = *reinterpret_cast<const float8*>(tab + ci0);

    float8 cpack, spack;
#pragma unroll
    for (int i = 0; i < 8; ++i) {
        float f = pos * fr[i];
        // max |f| = 511 rad ≈ 81.3 revolutions — inside v_sin_f32 valid range;
        // native accuracy ~4e-4 abs, threshold is 2e-2.
        spack[i] = __sinf(f);
        cpack[i] = __cosf(f);
    }

    const long long base = (long long)p * dim + chbase;
    // cos: original half + duplicated half
    *reinterpret_cast<float8*>(out + base)       = cpack;
    *reinterpret_cast<float8*>(out + base + dup) = cpack;
    // sin
    *reinterpret_cast<float8*>(out + sin_off + base)       = spack;
    *reinterpret_cast<float8*>(out + sin_off + base + dup) = spack;
}

extern "C" void kernel_launch(void* const* d_in, const int* in_sizes, int n_in,
                              void* d_out, int out_size, void* d_ws, size_t ws_size,
                              hipStream_t stream) {
    // inputs: [0]=x (f32, unused), [1]=inv_freq_x (f32), [2]=inv_freq_y (f32),
    //         [3]=height (int32), [4]=width (int32)
    const float* ifx = (const float*)d_in[1];
    const float* ify = (const float*)d_in[2];
    const int* wptr  = (const int*)d_in[4];
    float* out = (float*)d_out;

    const int dimx = 2 * in_sizes[1];      // 64
    const int dimy = 2 * in_sizes[2];      // 64
    const int dim  = dimx + dimy;          // 128
    const int rows = in_sizes[0] / dim;    // H*W = 262144

    const int tpr   = dim >> 4;            // 8 threads per row
    const int total = rows * tpr;          // 2,097,152
    const int block = 256;
    const int grid  = (total + block - 1) / block;   // 8192

    if (dimx == 64 && dimy == 64) {
        rope2d_kernel<64, 64><<<grid, block, 0, stream>>>(ifx, ify, wptr, out, rows, dimx, dimy);
    } else {
        rope2d_kernel<0, 0><<<grid, block, 0, stream>>>(ifx, ify, wptr, out, rows, dimx, dimy);
    }
}

// Round 3
// 321.180 us; speedup vs baseline: 1.0388x; 1.0388x over previous
//
#include <hip/hip_runtime.h>

// RoPE2D cos/sin table generator — float32, fully dense store mapping.
// Output: [cos_2d (rows*dim)] ++ [sin_2d (rows*dim)], rows = H*W, dim = dimx+dimy.
// Row p = y*W + x. Channel c:
//   c in [0, dimx):   val = trig(x * ifx[c mod (dimx/2)])
//   c in [dimx, dim): val = trig(y * ify[(c-dimx) mod (dimy/2)])
// One thread = 4 contiguous output floats -> single lane-contiguous dwordx4 store.

typedef __attribute__((ext_vector_type(4))) float float4v;

// Fast path: dimx = dimy = 64 (dim = 128, half-tables of 32). fidx = ch & 31 for both halves.
__global__ __launch_bounds__(256) void rope2d_fast(
    const float* __restrict__ ifx,
    const float* __restrict__ ify,
    const int* __restrict__ wptr,
    float* __restrict__ out,
    int rows)
{
    const int idx = blockIdx.x * blockDim.x + threadIdx.x;
    const int total4 = rows << 6;            // 2*rows*128/4
    if (idx >= total4) return;

    const int e = idx << 2;                  // element offset in flat output
    const int half = rows << 7;              // rows*128
    const bool is_sin = e >= half;           // wave-uniform (half % 256 == 0 when rows even)
    const int e2 = is_sin ? e - half : e;

    const int p  = e2 >> 7;                  // row
    const int ch = e2 & 127;                 // channel of first of 4 (4-aligned)

    const int W = *wptr;
    int xw, yh;
    if ((W & (W - 1)) == 0) {
        const int s = __ffs(W) - 1;
        xw = p & (W - 1);
        yh = p >> s;
    } else {
        xw = p % W;
        yh = p / W;
    }

    // channel quadrant: [0,64) -> x-table, [64,128) -> y-table; fidx = ch & 31 either way
    const bool use_x = ch < 64;
    const float pos = use_x ? (float)xw : (float)yh;
    const float* tab = use_x ? ifx : ify;
    const float4v fr = *reinterpret_cast<const float4v*>(tab + (ch & 31)); // 16B, L1-resident

    float4v v;
#pragma unroll
    for (int i = 0; i < 4; ++i) {
        const float f = pos * fr[i];
        v[i] = is_sin ? __sinf(f) : __cosf(f);   // v_sin/v_cos, wave-uniform select
    }

    *reinterpret_cast<float4v*>(out + e) = v;    // dense dwordx4, lanes contiguous
}

// Generic path: arbitrary dimx/dimy (scalar per element).
__global__ __launch_bounds__(256) void rope2d_generic(
    const float* __restrict__ ifx,
    const float* __restrict__ ify,
    const int* __restrict__ wptr,
    float* __restrict__ out,
    int rows, int dimx, int dimy)
{
    const int dim = dimx + dimy;
    const long long total = 2LL * rows * dim;
    const long long e = (long long)(blockIdx.x * blockDim.x + threadIdx.x);
    if (e >= total) return;

    const long long halfo = (long long)rows * dim;
    const bool is_sin = e >= halfo;
    const long long e2 = is_sin ? e - halfo : e;
    const int p  = (int)(e2 / dim);
    const int ch = (int)(e2 % dim);

    const int W = *wptr;
    const int xw = p % W, yh = p / W;

    float pos, f;
    if (ch < dimx) { pos = (float)xw; f = ifx[ch % (dimx >> 1)]; }
    else           { pos = (float)yh; f = ify[(ch - dimx) % (dimy >> 1)]; }
    const float ang = pos * f;
    out[e] = is_sin ? __sinf(ang) : __cosf(ang);
}

extern "C" void kernel_launch(void* const* d_in, const int* in_sizes, int n_in,
                              void* d_out, int out_size, void* d_ws, size_t ws_size,
                              hipStream_t stream) {
    // inputs: [0]=x (f32, dtype-only), [1]=inv_freq_x (f32), [2]=inv_freq_y (f32),
    //         [3]=height (int32), [4]=width (int32)
    const float* ifx = (const float*)d_in[1];
    const float* ify = (const float*)d_in[2];
    const int* wptr  = (const int*)d_in[4];
    float* out = (float*)d_out;

    const int dimx = 2 * in_sizes[1];      // 64
    const int dimy = 2 * in_sizes[2];      // 64
    const int dim  = dimx + dimy;          // 128
    const int rows = in_sizes[0] / dim;    // H*W = 262144

    if (dimx == 64 && dimy == 64) {
        const int total4 = rows << 6;                      // 16,777,216 threads
        const int block = 256;
        const int grid = (total4 + block - 1) / block;     // 65,536
        rope2d_fast<<<grid, block, 0, stream>>>(ifx, ify, wptr, out, rows);
    } else {
        const long long total = 2LL * rows * dim;
        const int block = 256;
        const int grid = (int)((total + block - 1) / block);
        rope2d_generic<<<grid, block, 0, stream>>>(ifx, ify, wptr, out, rows, dimx, dimy);
    }
}